// Round 10
// baseline (689.063 us; speedup 1.0000x reference)
//
#include <hip/hip_runtime.h>
#include <math.h>

constexpr int NN = 50000;
constexpr int NE = 600000;
constexpr int NG = 256;
constexpr int SB = (NN + 255) / 256;  // scan blocks = 196
constexpr float kBnEps = 1e-5f;
constexpr float kSlope = 0.2f;

typedef _Float16 f16x8 __attribute__((ext_vector_type(8)));
typedef float f32x16 __attribute__((ext_vector_type(16)));

__device__ __forceinline__ float rdlane(float v, int l) {
    return __builtin_bit_cast(float, __builtin_amdgcn_readlane(__builtin_bit_cast(int, v), l));
}

// DPP-based add: v += v[permuted lane] — VALU only, no LDS pipe.
template <int CTRL>
__device__ __forceinline__ float dppadd(float v) {
    int t = __builtin_amdgcn_mov_dpp(__builtin_bit_cast(int, v), CTRL, 0xF, 0xF, true);
    return v + __builtin_bit_cast(float, t);
}
// sum over each 16-lane group (all 16 lanes end with the group sum)
__device__ __forceinline__ float sum16(float v) {
    v = dppadd<0xB1>(v);    // quad_perm [1,0,3,2]
    v = dppadd<0x4E>(v);    // quad_perm [2,3,0,1]
    v = dppadd<0x141>(v);   // row_half_mirror
    v = dppadd<0x140>(v);   // row_mirror
    return v;
}

__device__ __forceinline__ float4 fma4(float a, float4 b, float4 c) {
    c.x = fmaf(a, b.x, c.x); c.y = fmaf(a, b.y, c.y);
    c.z = fmaf(a, b.z, c.z); c.w = fmaf(a, b.w, c.w);
    return c;
}

// ---------------- counting sort of edges by dst ----------------
__global__ __launch_bounds__(256) void k_hist(const int* __restrict__ dst, int* __restrict__ cnt)
{
    int e = blockIdx.x * 256 + threadIdx.x;
    if (e < NE) atomicAdd(&cnt[dst[e]], 1);
}

// per-block inclusive scan (unchanged)
__global__ __launch_bounds__(256) void k_scanA(const int* __restrict__ cnt,
                                               int* __restrict__ offs, int* __restrict__ bsum)
{
    __shared__ int s[256];
    int tid = threadIdx.x;
    int i = blockIdx.x * 256 + tid;
    int v = (i < NN) ? cnt[i] : 0;
    s[tid] = v;
    __syncthreads();
    #pragma unroll
    for (int d = 1; d < 256; d <<= 1) {
        int u = (tid >= d) ? s[tid - d] : 0;
        __syncthreads();
        s[tid] += u;
        __syncthreads();
    }
    if (i < NN) offs[i] = s[tid];           // block-local inclusive
    if (tid == 255) bsum[blockIdx.x] = s[255];
}

// r6: scanB folded in — each block reduces raw bsum[0..blockIdx) inline (196 ints).
__global__ __launch_bounds__(256) void k_scanC(const int* __restrict__ cnt,
                                               const int* __restrict__ bsum,
                                               int* __restrict__ offs, int* __restrict__ cur)
{
    __shared__ int sred[256];
    int t = threadIdx.x;
    int b = blockIdx.x;
    int v = (t < SB && t < b) ? bsum[t] : 0;
    sred[t] = v;
    __syncthreads();
    #pragma unroll
    for (int d = 128; d > 0; d >>= 1) {
        if (t < d) sred[t] += sred[t + d];
        __syncthreads();
    }
    int pre = sred[0];                      // exclusive prefix over block sums
    int i = b * 256 + t;
    if (i > NN) return;
    if (i == NN) { offs[NN] = NE; return; }
    int w = offs[i] - cnt[i] + pre;         // global exclusive
    offs[i] = w;
    cur[i] = w;
}

// r6: light scatter — ONE random 8B write per edge. se is the only edge-order
// array; attn reads edge_attr directly from ea via se[].y (r7).
__global__ __launch_bounds__(256) void k_scatter_light(const int* __restrict__ dst,
                                                       const int* __restrict__ src,
                                                       int* __restrict__ cur,
                                                       int2* __restrict__ se)
{
    int e = blockIdx.x * 256 + threadIdx.x;
    if (e < NE) {
        int p = atomicAdd(&cur[dst[e]], 1);
        se[p] = make_int2(src[e], e);
    }
}

// ---------------- W prep for MFMA dual linear (both layers, one dispatch) ----------
// Packed octet index: (kt*512 + col)*2 + g holds B[k = kt*16 + g*8 + i][col],
// col 0..255 -> WL, 256..511 -> WR.
__device__ __forceinline__ void prep_w_body(int T, const float* __restrict__ WL,
                                            const float* __restrict__ WR,
                                            _Float16* __restrict__ bhi,
                                            _Float16* __restrict__ blo)
{
    int g   = T & 1;
    int col = (T >> 1) & 511;
    int kt  = T >> 10;
    const float* W = (col < 256) ? WL : WR;
    int c = col & 255;
    f16x8 h8, l8;
    #pragma unroll
    for (int i = 0; i < 8; ++i) {
        float v = W[(size_t)(kt * 16 + g * 8 + i) * 256 + c];
        _Float16 hv = (_Float16)v;
        h8[i] = hv;
        l8[i] = (_Float16)(v - (float)hv);
    }
    *(f16x8*)(bhi + (size_t)T * 8) = h8;
    *(f16x8*)(blo + (size_t)T * 8) = l8;
}

// grid = 80 blocks: 0..15 -> layer0 (K=64), 16..79 -> layer1 (K=256)
__global__ __launch_bounds__(256) void k_prep_all(
    const float* __restrict__ Wl0, const float* __restrict__ Wr0,
    _Float16* __restrict__ bhi0, _Float16* __restrict__ blo0,
    const float* __restrict__ Wl1, const float* __restrict__ Wr1,
    _Float16* __restrict__ bhi1, _Float16* __restrict__ blo1)
{
    if (blockIdx.x < 16) {
        int T = blockIdx.x * 256 + threadIdx.x;
        prep_w_body(T, Wl0, Wr0, bhi0, blo0);
    } else {
        int T = (blockIdx.x - 16) * 256 + threadIdx.x;
        prep_w_body(T, Wl1, Wr1, bhi1, blo1);
    }
}

// ---------------- fused layer-0 MFMA (FROZEN r8 shape: BM=64, 512 thr) ----------
__global__ __launch_bounds__(512) void k_lin0_mfma(
    const float* __restrict__ x, const float* __restrict__ Win,
    const float* __restrict__ bin,
    const _Float16* __restrict__ Bhi, const _Float16* __restrict__ Blo,
    const float* __restrict__ bl, const float* __restrict__ br,
    float* __restrict__ outl, float* __restrict__ outr)
{
    __shared__ float h0s[64][68];        // +4 pad: rotates bank start per row
    __shared__ f16x8 Apack[2][4][128];   // [hi/lo][kt][slot] 16 KB
    int tid = threadIdx.x;
    int lane = tid & 63, wave = tid >> 6;
    int row0 = blockIdx.x * 64;

    // ---- phase 1: h0 for 8 rows/wave (8 waves = 64 rows), lane = channel ----
    {
        int rbase = row0 + wave * 8;
        float xreg[8];
        #pragma unroll
        for (int j = 0; j < 8; ++j) {
            int row = rbase + j; if (row >= NN) row = NN - 1;
            xreg[j] = x[(size_t)row * 64 + lane];
        }
        float b0 = bin[lane];
        float h0r[8];
        #pragma unroll
        for (int j = 0; j < 8; ++j) h0r[j] = b0;
        for (int k = 0; k < 64; ++k) {
            float w = Win[k * 64 + lane];
            #pragma unroll
            for (int j = 0; j < 8; ++j) h0r[j] = fmaf(rdlane(xreg[j], k), w, h0r[j]);
        }
        #pragma unroll
        for (int j = 0; j < 8; ++j)
            h0s[wave * 8 + j][lane] = fmaxf(h0r[j], 0.f);
    }
    __syncthreads();

    // ---- phase 2: each thread builds one f16 hi/lo fragment (row, 8 k) ----
    {
        int row = tid >> 3;               // 0..63
        int o = (tid & 7) * 8;            // k offset 0..56
        f16x8 hi8, lo8;
        #pragma unroll
        for (int i = 0; i < 8; ++i) {
            float v = h0s[row][o + i];
            _Float16 hv = (_Float16)v;
            hi8[i] = hv;
            lo8[i] = (_Float16)(v - (float)hv);
        }
        int kt = o >> 4, g2 = (o >> 3) & 1;
        int slot = (g2 * 64 + row) ^ kt;  // bijective within 128
        Apack[0][kt][slot] = hi8;
        Apack[1][kt][slot] = lo8;
    }
    __syncthreads();

    // ---- phase 3: MFMA over K=64 ----
    int g = lane >> 5;
    int rowtile = wave >> 2;              // 0 or 1
    int colbase = (wave & 3) * 128 + (lane & 31);
    int aslot = g * 64 + rowtile * 32 + (lane & 31);
    f32x16 acc[4];
    #pragma unroll
    for (int nt = 0; nt < 4; ++nt)
        #pragma unroll
        for (int r = 0; r < 16; ++r) acc[nt][r] = 0.f;

    const f16x8* bh = (const f16x8*)Bhi;
    const f16x8* bo = (const f16x8*)Blo;
    size_t fbase = (size_t)colbase * 2 + g;

    #pragma unroll 1
    for (int kt = 0; kt < 4; ++kt) {
        f16x8 ahi = Apack[0][kt][aslot ^ kt];
        f16x8 alo = Apack[1][kt][aslot ^ kt];
        f16x8 wh[4], wl[4];
        #pragma unroll
        for (int nt = 0; nt < 4; ++nt) {
            size_t fi = fbase + (size_t)kt * 1024 + nt * 64;
            wh[nt] = bh[fi];
            wl[nt] = bo[fi];
        }
        #pragma unroll
        for (int nt = 0; nt < 4; ++nt)
            acc[nt] = __builtin_amdgcn_mfma_f32_32x32x16_f16(ahi, wh[nt], acc[nt], 0, 0, 0);
        #pragma unroll
        for (int nt = 0; nt < 4; ++nt)
            acc[nt] = __builtin_amdgcn_mfma_f32_32x32x16_f16(alo, wh[nt], acc[nt], 0, 0, 0);
        #pragma unroll
        for (int nt = 0; nt < 4; ++nt)
            acc[nt] = __builtin_amdgcn_mfma_f32_32x32x16_f16(ahi, wl[nt], acc[nt], 0, 0, 0);
    }

    // ---- epilogue: bias add, scatter to xl / xr ----
    #pragma unroll
    for (int nt = 0; nt < 4; ++nt) {
        int col = colbase + nt * 32;          // 0..511
        bool isR = col >= 256;
        int c = isR ? col - 256 : col;
        float bv = isR ? br[c] : bl[c];
        float* outp = isR ? outr : outl;
        #pragma unroll
        for (int r = 0; r < 16; ++r) {
            int rowoff = (r & 3) + 8 * (r >> 2) + 4 * g;
            int grow = row0 + rowtile * 32 + rowoff;
            if (grow < NN)
                outp[(size_t)grow * 256 + c] = acc[nt][r] + bv;
        }
    }
}

// ---------------- MFMA dual linear K=256, v4: reg-resident B + 2-phase pipeline ----
// r9: register-resident B panels (128 VGPR/wave), zero vmem in K-loop (WIN -29).
// r10: (a) double-buffered Apack — next tile's h-loads issue BEFORE the MFMA
// cluster (independent, stay in flight across it; T14 issue-early/write-late);
// (b) one barrier per tile instead of two; (c) bn_finalize<256> folded into
// the prologue (bit-identical fp32 formula, LDS scale/shift) — one fewer
// dispatch. Accumulation order unchanged -> absmax unchanged.
__global__ __launch_bounds__(256) void k_linear2_mfma(
    const float* __restrict__ h, const _Float16* __restrict__ Bhi,
    const _Float16* __restrict__ Blo, const float* __restrict__ bl,
    const float* __restrict__ br, const float* __restrict__ bns,
    const float* __restrict__ bnq, const float* __restrict__ gam,
    const float* __restrict__ beta, float* __restrict__ outl,
    float* __restrict__ outr)
{
    __shared__ f16x8 Apack[2][2][16][64];   // [buf][hi/lo][kt][slot] 64 KB
    __shared__ float s_scale[256], s_shift[256];
    int tid = threadIdx.x;
    int lane = tid & 63, wave = tid >> 6;      // 4 waves = 4 colgroups
    int q = blockIdx.x & 3;                    // column quarter
    int mslot = blockIdx.x >> 2;               // 0..127
    int g = lane >> 5;
    int colbase = q * 128 + wave * 32 + (lane & 31);   // 0..511
    size_t fbase = (size_t)colbase * 2 + g;

    // ---- bn finalize (folded): 256 channels, one per thread ----
    {
        float inv_n = 1.f / (float)NN;
        float mu = bns[tid] * inv_n;
        float var = bnq[tid] * inv_n - mu * mu;
        float sc = gam[tid] / sqrtf(var + kBnEps);
        s_scale[tid] = sc;
        s_shift[tid] = fmaf(-mu, sc, beta[tid]);
    }

    // ---- B resident in registers: 16 kt x (hi+lo) = 128 VGPR ----
    const f16x8* bh = (const f16x8*)Bhi;
    const f16x8* bo = (const f16x8*)Blo;
    f16x8 BH[16], BL[16];
    #pragma unroll
    for (int kt = 0; kt < 16; ++kt) {
        BH[kt] = bh[fbase + (size_t)kt * 1024];
        BL[kt] = bo[fbase + (size_t)kt * 1024];
    }

    bool isR = colbase >= 256;
    int c = isR ? colbase - 256 : colbase;
    float bv = isR ? br[c] : bl[c];
    float* outp = isR ? outr : outl;

    int srow  = tid >> 3;            // staging row 0..31
    int koff = (tid & 7) * 32;       // staging k offset

    // load one tile's A rows (8 float4 = 32 floats) into registers
    auto load_tile = [&](int t, float4* va) {
        int grow = t * 32 + srow; if (grow >= NN) grow = NN - 1;
        const float* hp = h + (size_t)grow * 256 + koff;
        #pragma unroll
        for (int j = 0; j < 8; ++j) va[j] = *(const float4*)(hp + j * 4);
    };
    // BN+relu+split the registers into Apack[buf] (r1 layout, verbatim math)
    auto split_store = [&](int buf, const float4* va4) {
        #pragma unroll
        for (int j2 = 0; j2 < 4; ++j2) {
            int o = koff + j2 * 8;
            float4 a  = va4[j2 * 2];
            float4 b  = va4[j2 * 2 + 1];
            float4 s0 = *(const float4*)(s_scale + o);
            float4 s1 = *(const float4*)(s_scale + o + 4);
            float4 f0 = *(const float4*)(s_shift + o);
            float4 f1 = *(const float4*)(s_shift + o + 4);
            float va[8] = {
                fmaxf(fmaf(a.x, s0.x, f0.x), 0.f), fmaxf(fmaf(a.y, s0.y, f0.y), 0.f),
                fmaxf(fmaf(a.z, s0.z, f0.z), 0.f), fmaxf(fmaf(a.w, s0.w, f0.w), 0.f),
                fmaxf(fmaf(b.x, s1.x, f1.x), 0.f), fmaxf(fmaf(b.y, s1.y, f1.y), 0.f),
                fmaxf(fmaf(b.z, s1.z, f1.z), 0.f), fmaxf(fmaf(b.w, s1.w, f1.w), 0.f)};
            f16x8 hi8, lo8;
            #pragma unroll
            for (int i = 0; i < 8; ++i) {
                _Float16 hv = (_Float16)va[i];
                hi8[i] = hv;
                lo8[i] = (_Float16)(va[i] - (float)hv);
            }
            int kt = o >> 4, g2 = (o >> 3) & 1;
            int slot = (g2 * 32 + srow) ^ (kt & 7);
            Apack[buf][0][kt][slot] = hi8;
            Apack[buf][1][kt][slot] = lo8;
        }
    };

    constexpr int NT = (NN + 31) / 32;   // 1563 M-tiles

    // prologue: stage first tile into buf 0
    {
        float4 va[8];
        load_tile(mslot, va);
        __syncthreads();            // s_scale/s_shift ready
        split_store(0, va);
    }
    __syncthreads();

    int cur = 0;
    for (int t = mslot; t < NT; t += 128) {
        int tn = t + 128;
        bool more = tn < NT;
        float4 vb[8];
        if (more) load_tile(tn, vb);          // issue early; no use until split_store

        f32x16 acc;
        #pragma unroll
        for (int r = 0; r < 16; ++r) acc[r] = 0.f;
        #pragma unroll
        for (int kt = 0; kt < 16; ++kt) {
            f16x8 ahi = Apack[cur][0][kt][lane ^ (kt & 7)];
            f16x8 alo = Apack[cur][1][kt][lane ^ (kt & 7)];
            acc = __builtin_amdgcn_mfma_f32_32x32x16_f16(ahi, BH[kt], acc, 0, 0, 0);
            acc = __builtin_amdgcn_mfma_f32_32x32x16_f16(alo, BH[kt], acc, 0, 0, 0);
            acc = __builtin_amdgcn_mfma_f32_32x32x16_f16(ahi, BL[kt], acc, 0, 0, 0);
        }

        int row0 = t * 32;
        #pragma unroll
        for (int r = 0; r < 16; ++r) {
            int rowoff = (r & 3) + 8 * (r >> 2) + 4 * g;
            int grow = row0 + rowoff;
            if (grow < NN)
                outp[(size_t)grow * 256 + c] = acc[r] + bv;
        }

        if (more) split_store(cur ^ 1, vb);   // write NEXT buffer (no conflict
                                              // with this iter's MFMA reads)
        __syncthreads();                      // next tile's Apack ready for all
        cur ^= 1;
    }
}

// ---------------- fused attention (r3 arithmetic core, FROZEN; r7 memory side) ----
template <bool CONCAT, int NPW>
__global__ __launch_bounds__(256) void k_attn(
    const float* __restrict__ xl, const float* __restrict__ xr,
    const int2* __restrict__ se, const float* __restrict__ ea,
    const float* __restrict__ We, const float* __restrict__ att,
    const int* __restrict__ offs, const float* __restrict__ bias,
    float* __restrict__ out)
{
    int tid = threadIdx.x;
    int lane = tid & 63, wave = tid >> 6;
    float4 wr[16];
    #pragma unroll
    for (int k = 0; k < 16; ++k) wr[k] = ((const float4*)(We + k * 256))[lane];
    float4 ar = ((const float4*)att)[lane];

    int g16 = lane >> 4;
    int k16 = lane & 15;
    int nodebase = (blockIdx.x * 4 + wave) * NPW;
    if (nodebase >= NN) return;

    for (int nn = 0; nn < NPW; ++nn) {
        int n = nodebase + nn;
        if (n >= NN) break;
        int beg = offs[n], end = offs[n + 1];
        float4 xr4 = ((const float4*)(xr + (size_t)n * 256))[lane];

        float m = -INFINITY, ssum = 0.f;
        float4 acc = make_float4(0.f, 0.f, 0.f, 0.f);

        float nea = 0.f;
        float4 nx0, nx1, nx2, nx3;

        auto loadbatch = [&](int i) {
            int idx = i + g16;
            if (idx > end - 1) idx = end - 1;
            int2 sv2 = se[idx];
            nea = ea[(size_t)sv2.y * 16 + k16];
            int sv = sv2.x;
            int s0 = __builtin_amdgcn_readlane(sv, 0);
            int s1 = __builtin_amdgcn_readlane(sv, 16);
            int s2 = __builtin_amdgcn_readlane(sv, 32);
            int s3 = __builtin_amdgcn_readlane(sv, 48);
            nx0 = ((const float4*)(xl + (size_t)s0 * 256))[lane];
            nx1 = ((const float4*)(xl + (size_t)s1 * 256))[lane];
            nx2 = ((const float4*)(xl + (size_t)s2 * 256))[lane];
            nx3 = ((const float4*)(xl + (size_t)s3 * 256))[lane];
        };

        if (beg < end) loadbatch(beg);

        for (int i = beg; i < end; i += 4) {
            float cea = nea;
            float4 x0 = nx0, x1 = nx1, x2 = nx2, x3 = nx3;
            if (i + 4 < end) loadbatch(i + 4);

            float p[4];
            #pragma unroll
            for (int g = 0; g < 4; ++g) {
                float4 xg = (g == 0) ? x0 : (g == 1) ? x1 : (g == 2) ? x2 : x3;
                float4 em = xr4;  // xr folded into accumulator init
                #pragma unroll
                for (int k = 0; k < 16; ++k) {
                    float a = rdlane(cea, g * 16 + k);
                    em.x = fmaf(a, wr[k].x, em.x);
                    em.y = fmaf(a, wr[k].y, em.y);
                    em.z = fmaf(a, wr[k].z, em.z);
                    em.w = fmaf(a, wr[k].w, em.w);
                }
                float z0 = xg.x + em.x;
                float z1 = xg.y + em.y;
                float z2 = xg.z + em.z;
                float z3 = xg.w + em.w;
                z0 = (z0 > 0.f) ? z0 : kSlope * z0;
                z1 = (z1 > 0.f) ? z1 : kSlope * z1;
                z2 = (z2 > 0.f) ? z2 : kSlope * z2;
                z3 = (z3 > 0.f) ? z3 : kSlope * z3;
                float pv = fmaf(z0, ar.x, fmaf(z1, ar.y, fmaf(z2, ar.z, z3 * ar.w)));
                pv = sum16(pv);  // per-head logit (16-lane group), VALU-only DPP
                p[g] = (i + g < end) ? pv : -INFINITY;
            }
            float pm = fmaxf(fmaxf(p[0], p[1]), fmaxf(p[2], p[3]));
            float mn = fmaxf(m, pm);
            float sc = __expf(m - mn);
            float w0 = __expf(p[0] - mn);
            float w1 = __expf(p[1] - mn);
            float w2 = __expf(p[2] - mn);
            float w3 = __expf(p[3] - mn);
            ssum = fmaf(ssum, sc, (w0 + w1) + (w2 + w3));
            acc.x = fmaf(acc.x, sc, fmaf(w0, x0.x, fmaf(w1, x1.x, fmaf(w2, x2.x, w3 * x3.x))));
            acc.y = fmaf(acc.y, sc, fmaf(w0, x0.y, fmaf(w1, x1.y, fmaf(w2, x2.y, w3 * x3.y))));
            acc.z = fmaf(acc.z, sc, fmaf(w0, x0.z, fmaf(w1, x1.z, fmaf(w2, x2.z, w3 * x3.z))));
            acc.w = fmaf(acc.w, sc, fmaf(w0, x0.w, fmaf(w1, x1.w, fmaf(w2, x2.w, w3 * x3.w))));
            m = mn;
        }

        float inv = 1.f / (ssum + 1e-16f);
        if (CONCAT) {
            float4 b4 = ((const float4*)bias)[lane];
            float4 o;
            o.x = fmaf(acc.x, inv, b4.x);
            o.y = fmaf(acc.y, inv, b4.y);
            o.z = fmaf(acc.z, inv, b4.z);
            o.w = fmaf(acc.w, inv, b4.w);
            ((float4*)(out + (size_t)n * 256))[lane] = o;
        } else {
            float v0 = acc.x * inv, v1 = acc.y * inv, v2 = acc.z * inv, v3 = acc.w * inv;
            v0 += __shfl_xor(v0, 16, 64); v0 += __shfl_xor(v0, 32, 64);
            v1 += __shfl_xor(v1, 16, 64); v1 += __shfl_xor(v1, 32, 64);
            v2 += __shfl_xor(v2, 16, 64); v2 += __shfl_xor(v2, 32, 64);
            v3 += __shfl_xor(v3, 16, 64); v3 += __shfl_xor(v3, 32, 64);
            if (lane < 16) {
                float4 b4 = ((const float4*)bias)[lane];
                float4 o;
                o.x = fmaf(0.25f, v0, b4.x);
                o.y = fmaf(0.25f, v1, b4.y);
                o.z = fmaf(0.25f, v2, b4.z);
                o.w = fmaf(0.25f, v3, b4.w);
                ((float4*)(out + (size_t)n * 64))[lane] = o;
            }
        }
    }
}

// ---------------- batchnorm stats (sum, sumsq per channel) ----------------
template <int CH>
__global__ __launch_bounds__(256) void k_bn_stats(const float* __restrict__ h,
                                                  float* __restrict__ sum,
                                                  float* __restrict__ sumsq)
{
    constexpr int RP = 256 / CH;
    int tid = threadIdx.x;
    int c = tid % CH;
    int rsub = tid / CH;
    float s = 0.f, q = 0.f;
    #pragma unroll 4
    for (int n = blockIdx.x * RP + rsub; n < NN; n += gridDim.x * RP) {
        float v = h[(size_t)n * CH + c];
        s += v; q = fmaf(v, v, q);
    }
    __shared__ float ls[256], lq[256];
    ls[tid] = s; lq[tid] = q;
    __syncthreads();
    if (tid < CH) {
        #pragma unroll
        for (int r = 1; r < RP; ++r) { s += ls[tid + r * CH]; q += lq[tid + r * CH]; }
        atomicAdd(&sum[tid], s);
        atomicAdd(&sumsq[tid], q);
    }
}

// ---------------- fused BN-finalize + BN + mean-pool + MLP head ----------------
__global__ __launch_bounds__(256) void k_pool_mlp(
    const float* __restrict__ h2, const float* __restrict__ bns,
    const float* __restrict__ bnq, const float* __restrict__ gam,
    const float* __restrict__ beta, const int* __restrict__ batch,
    const float* __restrict__ Wm1, const float* __restrict__ bm1,
    const float* __restrict__ Wm2, const float* __restrict__ bm2,
    const float* __restrict__ Wm3, const float* __restrict__ bm3,
    float* __restrict__ out)
{
    int g = blockIdx.x, tid = threadIdx.x;
    int lane = tid & 63, wave = tid >> 6;
    __shared__ int sb[2];
    if (tid < 2) {
        int target = g + tid;
        int lo = 0, hi = NN;
        while (lo < hi) {
            int mid = (lo + hi) >> 1;
            if (batch[mid] < target) lo = mid + 1; else hi = mid;
        }
        sb[tid] = lo;
    }
    __syncthreads();
    int s = sb[0], e = sb[1];
    float inv_n = 1.f / (float)NN;
    float mu = bns[lane] * inv_n;
    float var = bnq[lane] * inv_n - mu * mu;
    float sc = gam[lane] / sqrtf(var + kBnEps);
    float sh = fmaf(-mu, sc, beta[lane]);
    float acc = 0.f;
    #pragma unroll 4
    for (int n = s + wave; n < e; n += 4)
        acc += fmaf(h2[(size_t)n * 64 + lane], sc, sh);
    __shared__ float red[4][64];
    red[wave][lane] = acc;
    __syncthreads();
    __shared__ float p[64], z1[32], z2[16];
    if (tid < 64) {
        float cnt = (float)(e - s);
        float a = red[0][tid] + red[1][tid] + red[2][tid] + red[3][tid];
        p[tid] = a / fmaxf(cnt, 1.f);
    }
    __syncthreads();
    if (tid < 32) {
        float a = bm1[tid];
        #pragma unroll
        for (int k = 0; k < 64; ++k) a = fmaf(p[k], Wm1[k * 32 + tid], a);
        z1[tid] = fmaxf(a, 0.f);
    }
    __syncthreads();
    if (tid < 16) {
        float a = bm2[tid];
        #pragma unroll
        for (int k = 0; k < 32; ++k) a = fmaf(z1[k], Wm2[k * 16 + tid], a);
        z2[tid] = fmaxf(a, 0.f);
    }
    __syncthreads();
    if (tid == 0) {
        float a = bm3[0];
        #pragma unroll
        for (int k = 0; k < 16; ++k) a = fmaf(z2[k], Wm3[k], a);
        out[g] = a;
    }
}

// ---------------- host launcher ----------------
extern "C" void kernel_launch(void* const* d_in, const int* in_sizes, int n_in,
                              void* d_out, int out_size, void* d_ws, size_t ws_size,
                              hipStream_t stream)
{
    const float* x     = (const float*)d_in[0];
    const float* ea    = (const float*)d_in[1];
    const int*   ei    = (const int*)d_in[2];
    const int*   bat   = (const int*)d_in[3];
    const float* W_in  = (const float*)d_in[4];
    const float* b_in  = (const float*)d_in[5];
    const float* Wl0   = (const float*)d_in[6];
    const float* bl0   = (const float*)d_in[7];
    const float* Wr0   = (const float*)d_in[8];
    const float* br0   = (const float*)d_in[9];
    const float* We0   = (const float*)d_in[10];
    const float* att0  = (const float*)d_in[11];
    const float* bias0 = (const float*)d_in[12];
    const float* g0    = (const float*)d_in[13];
    const float* beta0 = (const float*)d_in[14];
    const float* Wl1   = (const float*)d_in[15];
    const float* bl1   = (const float*)d_in[16];
    const float* Wr1   = (const float*)d_in[17];
    const float* br1   = (const float*)d_in[18];
    const float* We1   = (const float*)d_in[19];
    const float* att1  = (const float*)d_in[20];
    const float* bias1 = (const float*)d_in[21];
    const float* g1    = (const float*)d_in[22];
    const float* beta1 = (const float*)d_in[23];
    const float* Wm1   = (const float*)d_in[24];
    const float* bm1   = (const float*)d_in[25];
    const float* Wm2   = (const float*)d_in[26];
    const float* bm2   = (const float*)d_in[27];
    const float* Wm3   = (const float*)d_in[28];
    const float* bm3   = (const float*)d_in[29];
    const int* src = ei;
    const int* dst = ei + NE;
    float* out = (float*)d_out;

    char* p = (char*)d_ws;
    auto take = [&](size_t nbytes) -> char* {
        char* q = p;
        p += (nbytes + 255) & ~(size_t)255;
        return q;
    };
    // ---- zero zone (one memset) ----
    char* z0 = p;
    int*   hist   = (int*)take((size_t)NN * 4);
    float* bns0   = (float*)take(256 * 4);
    float* bnq0   = (float*)take(256 * 4);
    float* bns1   = (float*)take(64 * 4);
    float* bnq1   = (float*)take(64 * 4);
    size_t zbytes = (size_t)(p - z0);
    // ---- rest of workspace ----
    int*   offs   = (int*)take((size_t)(NN + 1) * 4);
    int*   curs   = (int*)take((size_t)NN * 4);
    int*   bsum   = (int*)take((size_t)SB * 4);
    int2*  se     = (int2*)take((size_t)NE * 8);
    float* h2     = (float*)take((size_t)NN * 64 * 4);
    float* xl     = (float*)take((size_t)NN * 256 * 4);
    float* xr     = (float*)take((size_t)NN * 256 * 4);
    float* h1     = (float*)take((size_t)NN * 256 * 4);
    _Float16* Bhi1 = (_Float16*)take((size_t)256 * 512 * 2);
    _Float16* Blo1 = (_Float16*)take((size_t)256 * 512 * 2);
    _Float16* Bhi0 = (_Float16*)take((size_t)64 * 512 * 2);
    _Float16* Blo0 = (_Float16*)take((size_t)64 * 512 * 2);

    hipMemsetAsync(z0, 0, zbytes, stream);

    k_hist<<<(NE + 255) / 256, 256, 0, stream>>>(dst, hist);
    k_prep_all<<<80, 256, 0, stream>>>(Wl0, Wr0, Bhi0, Blo0, Wl1, Wr1, Bhi1, Blo1);
    k_scanA<<<SB, 256, 0, stream>>>(hist, offs, bsum);
    k_scanC<<<SB, 256, 0, stream>>>(hist, bsum, offs, curs);
    k_scatter_light<<<(NE + 255) / 256, 256, 0, stream>>>(dst, src, curs, se);

    constexpr int NPW = 2;
    int attn_blocks = (NN + 4 * NPW - 1) / (4 * NPW);
    int lin0_blocks = (NN + 63) / 64;

    // ---- GATv2 layer 0 (input proj fused into MFMA dual linear) ----
    k_lin0_mfma<<<lin0_blocks, 512, 0, stream>>>(
        x, W_in, b_in, Bhi0, Blo0, bl0, br0, xl, xr);
    k_attn<true, NPW><<<attn_blocks, 256, 0, stream>>>(
        xl, xr, se, ea, We0, att0, offs, bias0, h1);
    k_bn_stats<256><<<1024, 256, 0, stream>>>(h1, bns0, bnq0);

    // ---- GATv2 layer 1: MFMA dual linear v4 (reg-B + 2-phase + BN fold) ----
    k_linear2_mfma<<<512, 256, 0, stream>>>(
        h1, Bhi1, Blo1, bl1, br1, bns0, bnq0, g0, beta0, xl, xr);
    k_attn<false, NPW><<<attn_blocks, 256, 0, stream>>>(
        xl, xr, se, ea, We1, att1, offs, bias1, h2);
    k_bn_stats<64><<<1024, 256, 0, stream>>>(h2, bns1, bnq1);

    // ---- fused BN-finalize + BN + pool + MLP (graph bounds inline) ----
    k_pool_mlp<<<NG, 256, 0, stream>>>(h2, bns1, bnq1, g1, beta1, bat,
                                       Wm1, bm1, Wm2, bm2, Wm3, bm3, out);
}

// Round 11
// 668.268 us; speedup vs baseline: 1.0311x; 1.0311x over previous
//
#include <hip/hip_runtime.h>
#include <math.h>

constexpr int NN = 50000;
constexpr int NE = 600000;
constexpr int NG = 256;
constexpr int SB = (NN + 255) / 256;  // scan blocks = 196
constexpr float kBnEps = 1e-5f;
constexpr float kSlope = 0.2f;

typedef _Float16 f16x8 __attribute__((ext_vector_type(8)));
typedef float f32x16 __attribute__((ext_vector_type(16)));

__device__ __forceinline__ float rdlane(float v, int l) {
    return __builtin_bit_cast(float, __builtin_amdgcn_readlane(__builtin_bit_cast(int, v), l));
}

// DPP-based add: v += v[permuted lane] — VALU only, no LDS pipe.
template <int CTRL>
__device__ __forceinline__ float dppadd(float v) {
    int t = __builtin_amdgcn_mov_dpp(__builtin_bit_cast(int, v), CTRL, 0xF, 0xF, true);
    return v + __builtin_bit_cast(float, t);
}
// sum over each 16-lane group (all 16 lanes end with the group sum)
__device__ __forceinline__ float sum16(float v) {
    v = dppadd<0xB1>(v);    // quad_perm [1,0,3,2]
    v = dppadd<0x4E>(v);    // quad_perm [2,3,0,1]
    v = dppadd<0x141>(v);   // row_half_mirror
    v = dppadd<0x140>(v);   // row_mirror
    return v;
}

__device__ __forceinline__ float4 fma4(float a, float4 b, float4 c) {
    c.x = fmaf(a, b.x, c.x); c.y = fmaf(a, b.y, c.y);
    c.z = fmaf(a, b.z, c.z); c.w = fmaf(a, b.w, c.w);
    return c;
}

// ---------------- counting sort of edges by dst ----------------
__global__ __launch_bounds__(256) void k_hist(const int* __restrict__ dst, int* __restrict__ cnt)
{
    int e = blockIdx.x * 256 + threadIdx.x;
    if (e < NE) atomicAdd(&cnt[dst[e]], 1);
}

// per-block inclusive scan (unchanged)
__global__ __launch_bounds__(256) void k_scanA(const int* __restrict__ cnt,
                                               int* __restrict__ offs, int* __restrict__ bsum)
{
    __shared__ int s[256];
    int tid = threadIdx.x;
    int i = blockIdx.x * 256 + tid;
    int v = (i < NN) ? cnt[i] : 0;
    s[tid] = v;
    __syncthreads();
    #pragma unroll
    for (int d = 1; d < 256; d <<= 1) {
        int u = (tid >= d) ? s[tid - d] : 0;
        __syncthreads();
        s[tid] += u;
        __syncthreads();
    }
    if (i < NN) offs[i] = s[tid];           // block-local inclusive
    if (tid == 255) bsum[blockIdx.x] = s[255];
}

// r6: scanB folded in — each block reduces raw bsum[0..blockIdx) inline (196 ints).
__global__ __launch_bounds__(256) void k_scanC(const int* __restrict__ cnt,
                                               const int* __restrict__ bsum,
                                               int* __restrict__ offs, int* __restrict__ cur)
{
    __shared__ int sred[256];
    int t = threadIdx.x;
    int b = blockIdx.x;
    int v = (t < SB && t < b) ? bsum[t] : 0;
    sred[t] = v;
    __syncthreads();
    #pragma unroll
    for (int d = 128; d > 0; d >>= 1) {
        if (t < d) sred[t] += sred[t + d];
        __syncthreads();
    }
    int pre = sred[0];                      // exclusive prefix over block sums
    int i = b * 256 + t;
    if (i > NN) return;
    if (i == NN) { offs[NN] = NE; return; }
    int w = offs[i] - cnt[i] + pre;         // global exclusive
    offs[i] = w;
    cur[i] = w;
}

// r6: light scatter — ONE random 8B write per edge. se is the only edge-order
// array; attn reads edge_attr directly from ea via se[].y (r7).
__global__ __launch_bounds__(256) void k_scatter_light(const int* __restrict__ dst,
                                                       const int* __restrict__ src,
                                                       int* __restrict__ cur,
                                                       int2* __restrict__ se)
{
    int e = blockIdx.x * 256 + threadIdx.x;
    if (e < NE) {
        int p = atomicAdd(&cur[dst[e]], 1);
        se[p] = make_int2(src[e], e);
    }
}

// ---------------- W prep for MFMA dual linear (both layers, one dispatch) ----------
// Packed octet index: (kt*512 + col)*2 + g holds B[k = kt*16 + g*8 + i][col],
// col 0..255 -> WL, 256..511 -> WR.
__device__ __forceinline__ void prep_w_body(int T, const float* __restrict__ WL,
                                            const float* __restrict__ WR,
                                            _Float16* __restrict__ bhi,
                                            _Float16* __restrict__ blo)
{
    int g   = T & 1;
    int col = (T >> 1) & 511;
    int kt  = T >> 10;
    const float* W = (col < 256) ? WL : WR;
    int c = col & 255;
    f16x8 h8, l8;
    #pragma unroll
    for (int i = 0; i < 8; ++i) {
        float v = W[(size_t)(kt * 16 + g * 8 + i) * 256 + c];
        _Float16 hv = (_Float16)v;
        h8[i] = hv;
        l8[i] = (_Float16)(v - (float)hv);
    }
    *(f16x8*)(bhi + (size_t)T * 8) = h8;
    *(f16x8*)(blo + (size_t)T * 8) = l8;
}

// grid = 80 blocks: 0..15 -> layer0 (K=64), 16..79 -> layer1 (K=256)
__global__ __launch_bounds__(256) void k_prep_all(
    const float* __restrict__ Wl0, const float* __restrict__ Wr0,
    _Float16* __restrict__ bhi0, _Float16* __restrict__ blo0,
    const float* __restrict__ Wl1, const float* __restrict__ Wr1,
    _Float16* __restrict__ bhi1, _Float16* __restrict__ blo1)
{
    if (blockIdx.x < 16) {
        int T = blockIdx.x * 256 + threadIdx.x;
        prep_w_body(T, Wl0, Wr0, bhi0, blo0);
    } else {
        int T = (blockIdx.x - 16) * 256 + threadIdx.x;
        prep_w_body(T, Wl1, Wr1, bhi1, blo1);
    }
}

// ---------------- fused layer-0 MFMA (FROZEN r8 shape: BM=64, 512 thr) ----------
__global__ __launch_bounds__(512) void k_lin0_mfma(
    const float* __restrict__ x, const float* __restrict__ Win,
    const float* __restrict__ bin,
    const _Float16* __restrict__ Bhi, const _Float16* __restrict__ Blo,
    const float* __restrict__ bl, const float* __restrict__ br,
    float* __restrict__ outl, float* __restrict__ outr)
{
    __shared__ float h0s[64][68];        // +4 pad: rotates bank start per row
    __shared__ f16x8 Apack[2][4][128];   // [hi/lo][kt][slot] 16 KB
    int tid = threadIdx.x;
    int lane = tid & 63, wave = tid >> 6;
    int row0 = blockIdx.x * 64;

    // ---- phase 1: h0 for 8 rows/wave (8 waves = 64 rows), lane = channel ----
    {
        int rbase = row0 + wave * 8;
        float xreg[8];
        #pragma unroll
        for (int j = 0; j < 8; ++j) {
            int row = rbase + j; if (row >= NN) row = NN - 1;
            xreg[j] = x[(size_t)row * 64 + lane];
        }
        float b0 = bin[lane];
        float h0r[8];
        #pragma unroll
        for (int j = 0; j < 8; ++j) h0r[j] = b0;
        for (int k = 0; k < 64; ++k) {
            float w = Win[k * 64 + lane];
            #pragma unroll
            for (int j = 0; j < 8; ++j) h0r[j] = fmaf(rdlane(xreg[j], k), w, h0r[j]);
        }
        #pragma unroll
        for (int j = 0; j < 8; ++j)
            h0s[wave * 8 + j][lane] = fmaxf(h0r[j], 0.f);
    }
    __syncthreads();

    // ---- phase 2: each thread builds one f16 hi/lo fragment (row, 8 k) ----
    {
        int row = tid >> 3;               // 0..63
        int o = (tid & 7) * 8;            // k offset 0..56
        f16x8 hi8, lo8;
        #pragma unroll
        for (int i = 0; i < 8; ++i) {
            float v = h0s[row][o + i];
            _Float16 hv = (_Float16)v;
            hi8[i] = hv;
            lo8[i] = (_Float16)(v - (float)hv);
        }
        int kt = o >> 4, g2 = (o >> 3) & 1;
        int slot = (g2 * 64 + row) ^ kt;  // bijective within 128
        Apack[0][kt][slot] = hi8;
        Apack[1][kt][slot] = lo8;
    }
    __syncthreads();

    // ---- phase 3: MFMA over K=64 ----
    int g = lane >> 5;
    int rowtile = wave >> 2;              // 0 or 1
    int colbase = (wave & 3) * 128 + (lane & 31);
    int aslot = g * 64 + rowtile * 32 + (lane & 31);
    f32x16 acc[4];
    #pragma unroll
    for (int nt = 0; nt < 4; ++nt)
        #pragma unroll
        for (int r = 0; r < 16; ++r) acc[nt][r] = 0.f;

    const f16x8* bh = (const f16x8*)Bhi;
    const f16x8* bo = (const f16x8*)Blo;
    size_t fbase = (size_t)colbase * 2 + g;

    #pragma unroll 1
    for (int kt = 0; kt < 4; ++kt) {
        f16x8 ahi = Apack[0][kt][aslot ^ kt];
        f16x8 alo = Apack[1][kt][aslot ^ kt];
        f16x8 wh[4], wl[4];
        #pragma unroll
        for (int nt = 0; nt < 4; ++nt) {
            size_t fi = fbase + (size_t)kt * 1024 + nt * 64;
            wh[nt] = bh[fi];
            wl[nt] = bo[fi];
        }
        #pragma unroll
        for (int nt = 0; nt < 4; ++nt)
            acc[nt] = __builtin_amdgcn_mfma_f32_32x32x16_f16(ahi, wh[nt], acc[nt], 0, 0, 0);
        #pragma unroll
        for (int nt = 0; nt < 4; ++nt)
            acc[nt] = __builtin_amdgcn_mfma_f32_32x32x16_f16(alo, wh[nt], acc[nt], 0, 0, 0);
        #pragma unroll
        for (int nt = 0; nt < 4; ++nt)
            acc[nt] = __builtin_amdgcn_mfma_f32_32x32x16_f16(ahi, wl[nt], acc[nt], 0, 0, 0);
    }

    // ---- epilogue: bias add, scatter to xl / xr ----
    #pragma unroll
    for (int nt = 0; nt < 4; ++nt) {
        int col = colbase + nt * 32;          // 0..511
        bool isR = col >= 256;
        int c = isR ? col - 256 : col;
        float bv = isR ? br[c] : bl[c];
        float* outp = isR ? outr : outl;
        #pragma unroll
        for (int r = 0; r < 16; ++r) {
            int rowoff = (r & 3) + 8 * (r >> 2) + 4 * g;
            int grow = row0 + rowtile * 32 + rowoff;
            if (grow < NN)
                outp[(size_t)grow * 256 + c] = acc[nt][r] + bv;
        }
    }
}

// ---------------- MFMA dual linear K=256, v5: reg-resident B, half-column blocks ----
// r9 (WIN -29): register-resident B panels (128 VGPR/wave), zero vmem in the
// K-loop, simple serial tile loop (r10's dbuf/2-phase pipeline REGRESSED +12 —
// no latency left to hide, occupancy/pressure cost dominated; reverted).
// r11: geometry only — 2 column-halves x 512-thr blocks (8 waves x 32 cols)
// instead of 4 quarters x 256-thr: A re-read x4 -> x2 (205 -> 102 MB through
// L2/L3). Per-wave K-loop and accumulation order byte-identical to r9.
__global__ __launch_bounds__(512) void k_linear2_mfma(
    const float* __restrict__ h, const _Float16* __restrict__ Bhi,
    const _Float16* __restrict__ Blo, const float* __restrict__ bl,
    const float* __restrict__ br, const float* __restrict__ scale,
    const float* __restrict__ shift, float* __restrict__ outl,
    float* __restrict__ outr)
{
    __shared__ f16x8 Apack[2][16][64];   // [hi/lo][kt][slot] 32 KB
    int tid = threadIdx.x;
    int lane = tid & 63, wave = tid >> 6;      // 8 waves = 8 colgroups
    int q = blockIdx.x & 1;                    // column half
    int mslot = blockIdx.x >> 1;               // 0..127
    int g = lane >> 5;
    int colbase = q * 256 + wave * 32 + (lane & 31);   // 0..511
    size_t fbase = (size_t)colbase * 2 + g;

    // ---- B resident in registers: 16 kt x (hi+lo) = 128 VGPR ----
    const f16x8* bh = (const f16x8*)Bhi;
    const f16x8* bo = (const f16x8*)Blo;
    f16x8 BH[16], BL[16];
    #pragma unroll
    for (int kt = 0; kt < 16; ++kt) {
        BH[kt] = bh[fbase + (size_t)kt * 1024];
        BL[kt] = bo[fbase + (size_t)kt * 1024];
    }

    bool isR = colbase >= 256;
    int c = isR ? colbase - 256 : colbase;
    float bv = isR ? br[c] : bl[c];
    float* outp = isR ? outr : outl;

    constexpr int NT = (NN + 31) / 32;   // 1563 M-tiles
    for (int t = mslot; t < NT; t += 128) {
        int row0 = t * 32;
        // ---- stage A: 32 rows x 256 k, BN+relu, split (r1 layout; 512 thr:
        //      each thread covers 16 k of one row) ----
        {
            int row  = tid >> 4;              // 0..31
            int koff = (tid & 15) * 16;       // 0..240
            int grow = row0 + row; if (grow >= NN) grow = NN - 1;
            const float* hp = h + (size_t)grow * 256 + koff;
            #pragma unroll
            for (int j2 = 0; j2 < 2; ++j2) {
                int o = koff + j2 * 8;
                float4 a  = *(const float4*)(hp + j2 * 8);
                float4 b  = *(const float4*)(hp + j2 * 8 + 4);
                float4 s0 = *(const float4*)(scale + o);
                float4 s1 = *(const float4*)(scale + o + 4);
                float4 f0 = *(const float4*)(shift + o);
                float4 f1 = *(const float4*)(shift + o + 4);
                float va[8] = {
                    fmaxf(fmaf(a.x, s0.x, f0.x), 0.f), fmaxf(fmaf(a.y, s0.y, f0.y), 0.f),
                    fmaxf(fmaf(a.z, s0.z, f0.z), 0.f), fmaxf(fmaf(a.w, s0.w, f0.w), 0.f),
                    fmaxf(fmaf(b.x, s1.x, f1.x), 0.f), fmaxf(fmaf(b.y, s1.y, f1.y), 0.f),
                    fmaxf(fmaf(b.z, s1.z, f1.z), 0.f), fmaxf(fmaf(b.w, s1.w, f1.w), 0.f)};
                f16x8 hi8, lo8;
                #pragma unroll
                for (int i = 0; i < 8; ++i) {
                    _Float16 hv = (_Float16)va[i];
                    hi8[i] = hv;
                    lo8[i] = (_Float16)(va[i] - (float)hv);
                }
                int kt = o >> 4, g2 = (o >> 3) & 1;
                int slot = (g2 * 32 + row) ^ (kt & 7);
                Apack[0][kt][slot] = hi8;
                Apack[1][kt][slot] = lo8;
            }
        }
        __syncthreads();

        f32x16 acc;
        #pragma unroll
        for (int r = 0; r < 16; ++r) acc[r] = 0.f;

        #pragma unroll
        for (int kt = 0; kt < 16; ++kt) {
            f16x8 ahi = Apack[0][kt][lane ^ (kt & 7)];
            f16x8 alo = Apack[1][kt][lane ^ (kt & 7)];
            acc = __builtin_amdgcn_mfma_f32_32x32x16_f16(ahi, BH[kt], acc, 0, 0, 0);
            acc = __builtin_amdgcn_mfma_f32_32x32x16_f16(alo, BH[kt], acc, 0, 0, 0);
            acc = __builtin_amdgcn_mfma_f32_32x32x16_f16(ahi, BL[kt], acc, 0, 0, 0);
        }
        __syncthreads();   // all waves done reading Apack before next stage

        #pragma unroll
        for (int r = 0; r < 16; ++r) {
            int rowoff = (r & 3) + 8 * (r >> 2) + 4 * g;
            int grow = row0 + rowoff;
            if (grow < NN)
                outp[(size_t)grow * 256 + c] = acc[r] + bv;
        }
    }
}

// ---------------- fused attention (r3 arithmetic core, FROZEN; r7 memory side) ----
template <bool CONCAT, int NPW>
__global__ __launch_bounds__(256) void k_attn(
    const float* __restrict__ xl, const float* __restrict__ xr,
    const int2* __restrict__ se, const float* __restrict__ ea,
    const float* __restrict__ We, const float* __restrict__ att,
    const int* __restrict__ offs, const float* __restrict__ bias,
    float* __restrict__ out)
{
    int tid = threadIdx.x;
    int lane = tid & 63, wave = tid >> 6;
    float4 wr[16];
    #pragma unroll
    for (int k = 0; k < 16; ++k) wr[k] = ((const float4*)(We + k * 256))[lane];
    float4 ar = ((const float4*)att)[lane];

    int g16 = lane >> 4;
    int k16 = lane & 15;
    int nodebase = (blockIdx.x * 4 + wave) * NPW;
    if (nodebase >= NN) return;

    for (int nn = 0; nn < NPW; ++nn) {
        int n = nodebase + nn;
        if (n >= NN) break;
        int beg = offs[n], end = offs[n + 1];
        float4 xr4 = ((const float4*)(xr + (size_t)n * 256))[lane];

        float m = -INFINITY, ssum = 0.f;
        float4 acc = make_float4(0.f, 0.f, 0.f, 0.f);

        float nea = 0.f;
        float4 nx0, nx1, nx2, nx3;

        auto loadbatch = [&](int i) {
            int idx = i + g16;
            if (idx > end - 1) idx = end - 1;
            int2 sv2 = se[idx];
            nea = ea[(size_t)sv2.y * 16 + k16];
            int sv = sv2.x;
            int s0 = __builtin_amdgcn_readlane(sv, 0);
            int s1 = __builtin_amdgcn_readlane(sv, 16);
            int s2 = __builtin_amdgcn_readlane(sv, 32);
            int s3 = __builtin_amdgcn_readlane(sv, 48);
            nx0 = ((const float4*)(xl + (size_t)s0 * 256))[lane];
            nx1 = ((const float4*)(xl + (size_t)s1 * 256))[lane];
            nx2 = ((const float4*)(xl + (size_t)s2 * 256))[lane];
            nx3 = ((const float4*)(xl + (size_t)s3 * 256))[lane];
        };

        if (beg < end) loadbatch(beg);

        for (int i = beg; i < end; i += 4) {
            float cea = nea;
            float4 x0 = nx0, x1 = nx1, x2 = nx2, x3 = nx3;
            if (i + 4 < end) loadbatch(i + 4);

            float p[4];
            #pragma unroll
            for (int g = 0; g < 4; ++g) {
                float4 xg = (g == 0) ? x0 : (g == 1) ? x1 : (g == 2) ? x2 : x3;
                float4 em = xr4;  // xr folded into accumulator init
                #pragma unroll
                for (int k = 0; k < 16; ++k) {
                    float a = rdlane(cea, g * 16 + k);
                    em.x = fmaf(a, wr[k].x, em.x);
                    em.y = fmaf(a, wr[k].y, em.y);
                    em.z = fmaf(a, wr[k].z, em.z);
                    em.w = fmaf(a, wr[k].w, em.w);
                }
                float z0 = xg.x + em.x;
                float z1 = xg.y + em.y;
                float z2 = xg.z + em.z;
                float z3 = xg.w + em.w;
                z0 = (z0 > 0.f) ? z0 : kSlope * z0;
                z1 = (z1 > 0.f) ? z1 : kSlope * z1;
                z2 = (z2 > 0.f) ? z2 : kSlope * z2;
                z3 = (z3 > 0.f) ? z3 : kSlope * z3;
                float pv = fmaf(z0, ar.x, fmaf(z1, ar.y, fmaf(z2, ar.z, z3 * ar.w)));
                pv = sum16(pv);  // per-head logit (16-lane group), VALU-only DPP
                p[g] = (i + g < end) ? pv : -INFINITY;
            }
            float pm = fmaxf(fmaxf(p[0], p[1]), fmaxf(p[2], p[3]));
            float mn = fmaxf(m, pm);
            float sc = __expf(m - mn);
            float w0 = __expf(p[0] - mn);
            float w1 = __expf(p[1] - mn);
            float w2 = __expf(p[2] - mn);
            float w3 = __expf(p[3] - mn);
            ssum = fmaf(ssum, sc, (w0 + w1) + (w2 + w3));
            acc.x = fmaf(acc.x, sc, fmaf(w0, x0.x, fmaf(w1, x1.x, fmaf(w2, x2.x, w3 * x3.x))));
            acc.y = fmaf(acc.y, sc, fmaf(w0, x0.y, fmaf(w1, x1.y, fmaf(w2, x2.y, w3 * x3.y))));
            acc.z = fmaf(acc.z, sc, fmaf(w0, x0.z, fmaf(w1, x1.z, fmaf(w2, x2.z, w3 * x3.z))));
            acc.w = fmaf(acc.w, sc, fmaf(w0, x0.w, fmaf(w1, x1.w, fmaf(w2, x2.w, w3 * x3.w))));
            m = mn;
        }

        float inv = 1.f / (ssum + 1e-16f);
        if (CONCAT) {
            float4 b4 = ((const float4*)bias)[lane];
            float4 o;
            o.x = fmaf(acc.x, inv, b4.x);
            o.y = fmaf(acc.y, inv, b4.y);
            o.z = fmaf(acc.z, inv, b4.z);
            o.w = fmaf(acc.w, inv, b4.w);
            ((float4*)(out + (size_t)n * 256))[lane] = o;
        } else {
            float v0 = acc.x * inv, v1 = acc.y * inv, v2 = acc.z * inv, v3 = acc.w * inv;
            v0 += __shfl_xor(v0, 16, 64); v0 += __shfl_xor(v0, 32, 64);
            v1 += __shfl_xor(v1, 16, 64); v1 += __shfl_xor(v1, 32, 64);
            v2 += __shfl_xor(v2, 16, 64); v2 += __shfl_xor(v2, 32, 64);
            v3 += __shfl_xor(v3, 16, 64); v3 += __shfl_xor(v3, 32, 64);
            if (lane < 16) {
                float4 b4 = ((const float4*)bias)[lane];
                float4 o;
                o.x = fmaf(0.25f, v0, b4.x);
                o.y = fmaf(0.25f, v1, b4.y);
                o.z = fmaf(0.25f, v2, b4.z);
                o.w = fmaf(0.25f, v3, b4.w);
                ((float4*)(out + (size_t)n * 64))[lane] = o;
            }
        }
    }
}

// ---------------- batchnorm stats (sum, sumsq per channel) ----------------
template <int CH>
__global__ __launch_bounds__(256) void k_bn_stats(const float* __restrict__ h,
                                                  float* __restrict__ sum,
                                                  float* __restrict__ sumsq)
{
    constexpr int RP = 256 / CH;
    int tid = threadIdx.x;
    int c = tid % CH;
    int rsub = tid / CH;
    float s = 0.f, q = 0.f;
    #pragma unroll 4
    for (int n = blockIdx.x * RP + rsub; n < NN; n += gridDim.x * RP) {
        float v = h[(size_t)n * CH + c];
        s += v; q = fmaf(v, v, q);
    }
    __shared__ float ls[256], lq[256];
    ls[tid] = s; lq[tid] = q;
    __syncthreads();
    if (tid < CH) {
        #pragma unroll
        for (int r = 1; r < RP; ++r) { s += ls[tid + r * CH]; q += lq[tid + r * CH]; }
        atomicAdd(&sum[tid], s);
        atomicAdd(&sumsq[tid], q);
    }
}

__global__ void k_bn_finalize(const float* __restrict__ sum, const float* __restrict__ sumsq,
                              const float* __restrict__ g, const float* __restrict__ beta,
                              float* __restrict__ scale, float* __restrict__ shift, int CH)
{
    int c = threadIdx.x;
    if (c >= CH) return;
    float inv_n = 1.f / (float)NN;
    float mu = sum[c] * inv_n;
    float var = sumsq[c] * inv_n - mu * mu;
    float sc = g[c] / sqrtf(var + kBnEps);
    scale[c] = sc;
    shift[c] = fmaf(-mu, sc, beta[c]);
}

// ---------------- fused BN-finalize + BN + mean-pool + MLP head ----------------
__global__ __launch_bounds__(256) void k_pool_mlp(
    const float* __restrict__ h2, const float* __restrict__ bns,
    const float* __restrict__ bnq, const float* __restrict__ gam,
    const float* __restrict__ beta, const int* __restrict__ batch,
    const float* __restrict__ Wm1, const float* __restrict__ bm1,
    const float* __restrict__ Wm2, const float* __restrict__ bm2,
    const float* __restrict__ Wm3, const float* __restrict__ bm3,
    float* __restrict__ out)
{
    int g = blockIdx.x, tid = threadIdx.x;
    int lane = tid & 63, wave = tid >> 6;
    __shared__ int sb[2];
    if (tid < 2) {
        int target = g + tid;
        int lo = 0, hi = NN;
        while (lo < hi) {
            int mid = (lo + hi) >> 1;
            if (batch[mid] < target) lo = mid + 1; else hi = mid;
        }
        sb[tid] = lo;
    }
    __syncthreads();
    int s = sb[0], e = sb[1];
    float inv_n = 1.f / (float)NN;
    float mu = bns[lane] * inv_n;
    float var = bnq[lane] * inv_n - mu * mu;
    float sc = gam[lane] / sqrtf(var + kBnEps);
    float sh = fmaf(-mu, sc, beta[lane]);
    float acc = 0.f;
    #pragma unroll 4
    for (int n = s + wave; n < e; n += 4)
        acc += fmaf(h2[(size_t)n * 64 + lane], sc, sh);
    __shared__ float red[4][64];
    red[wave][lane] = acc;
    __syncthreads();
    __shared__ float p[64], z1[32], z2[16];
    if (tid < 64) {
        float cnt = (float)(e - s);
        float a = red[0][tid] + red[1][tid] + red[2][tid] + red[3][tid];
        p[tid] = a / fmaxf(cnt, 1.f);
    }
    __syncthreads();
    if (tid < 32) {
        float a = bm1[tid];
        #pragma unroll
        for (int k = 0; k < 64; ++k) a = fmaf(p[k], Wm1[k * 32 + tid], a);
        z1[tid] = fmaxf(a, 0.f);
    }
    __syncthreads();
    if (tid < 16) {
        float a = bm2[tid];
        #pragma unroll
        for (int k = 0; k < 32; ++k) a = fmaf(z1[k], Wm2[k * 16 + tid], a);
        z2[tid] = fmaxf(a, 0.f);
    }
    __syncthreads();
    if (tid == 0) {
        float a = bm3[0];
        #pragma unroll
        for (int k = 0; k < 16; ++k) a = fmaf(z2[k], Wm3[k], a);
        out[g] = a;
    }
}

// ---------------- host launcher ----------------
extern "C" void kernel_launch(void* const* d_in, const int* in_sizes, int n_in,
                              void* d_out, int out_size, void* d_ws, size_t ws_size,
                              hipStream_t stream)
{
    const float* x     = (const float*)d_in[0];
    const float* ea    = (const float*)d_in[1];
    const int*   ei    = (const int*)d_in[2];
    const int*   bat   = (const int*)d_in[3];
    const float* W_in  = (const float*)d_in[4];
    const float* b_in  = (const float*)d_in[5];
    const float* Wl0   = (const float*)d_in[6];
    const float* bl0   = (const float*)d_in[7];
    const float* Wr0   = (const float*)d_in[8];
    const float* br0   = (const float*)d_in[9];
    const float* We0   = (const float*)d_in[10];
    const float* att0  = (const float*)d_in[11];
    const float* bias0 = (const float*)d_in[12];
    const float* g0    = (const float*)d_in[13];
    const float* beta0 = (const float*)d_in[14];
    const float* Wl1   = (const float*)d_in[15];
    const float* bl1   = (const float*)d_in[16];
    const float* Wr1   = (const float*)d_in[17];
    const float* br1   = (const float*)d_in[18];
    const float* We1   = (const float*)d_in[19];
    const float* att1  = (const float*)d_in[20];
    const float* bias1 = (const float*)d_in[21];
    const float* g1    = (const float*)d_in[22];
    const float* beta1 = (const float*)d_in[23];
    const float* Wm1   = (const float*)d_in[24];
    const float* bm1   = (const float*)d_in[25];
    const float* Wm2   = (const float*)d_in[26];
    const float* bm2   = (const float*)d_in[27];
    const float* Wm3   = (const float*)d_in[28];
    const float* bm3   = (const float*)d_in[29];
    const int* src = ei;
    const int* dst = ei + NE;
    float* out = (float*)d_out;

    char* p = (char*)d_ws;
    auto take = [&](size_t nbytes) -> char* {
        char* q = p;
        p += (nbytes + 255) & ~(size_t)255;
        return q;
    };
    // ---- zero zone (one memset) ----
    char* z0 = p;
    int*   hist   = (int*)take((size_t)NN * 4);
    float* bns0   = (float*)take(256 * 4);
    float* bnq0   = (float*)take(256 * 4);
    float* bns1   = (float*)take(64 * 4);
    float* bnq1   = (float*)take(64 * 4);
    size_t zbytes = (size_t)(p - z0);
    // ---- rest of workspace ----
    int*   offs   = (int*)take((size_t)(NN + 1) * 4);
    int*   curs   = (int*)take((size_t)NN * 4);
    int*   bsum   = (int*)take((size_t)SB * 4);
    int2*  se     = (int2*)take((size_t)NE * 8);
    float* h2     = (float*)take((size_t)NN * 64 * 4);
    float* xl     = (float*)take((size_t)NN * 256 * 4);
    float* xr     = (float*)take((size_t)NN * 256 * 4);
    float* h1     = (float*)take((size_t)NN * 256 * 4);
    float* scale0 = (float*)take(256 * 4);
    float* shift0 = (float*)take(256 * 4);
    _Float16* Bhi1 = (_Float16*)take((size_t)256 * 512 * 2);
    _Float16* Blo1 = (_Float16*)take((size_t)256 * 512 * 2);
    _Float16* Bhi0 = (_Float16*)take((size_t)64 * 512 * 2);
    _Float16* Blo0 = (_Float16*)take((size_t)64 * 512 * 2);

    hipMemsetAsync(z0, 0, zbytes, stream);

    k_hist<<<(NE + 255) / 256, 256, 0, stream>>>(dst, hist);
    k_prep_all<<<80, 256, 0, stream>>>(Wl0, Wr0, Bhi0, Blo0, Wl1, Wr1, Bhi1, Blo1);
    k_scanA<<<SB, 256, 0, stream>>>(hist, offs, bsum);
    k_scanC<<<SB, 256, 0, stream>>>(hist, bsum, offs, curs);
    k_scatter_light<<<(NE + 255) / 256, 256, 0, stream>>>(dst, src, curs, se);

    constexpr int NPW = 2;
    int attn_blocks = (NN + 4 * NPW - 1) / (4 * NPW);
    int lin0_blocks = (NN + 63) / 64;

    // ---- GATv2 layer 0 (input proj fused into MFMA dual linear) ----
    k_lin0_mfma<<<lin0_blocks, 512, 0, stream>>>(
        x, W_in, b_in, Bhi0, Blo0, bl0, br0, xl, xr);
    k_attn<true, NPW><<<attn_blocks, 256, 0, stream>>>(
        xl, xr, se, ea, We0, att0, offs, bias0, h1);
    k_bn_stats<256><<<1024, 256, 0, stream>>>(h1, bns0, bnq0);
    k_bn_finalize<<<1, 256, 0, stream>>>(bns0, bnq0, g0, beta0, scale0, shift0, 256);

    // ---- GATv2 layer 1: MFMA dual linear v5 (reg-B, half-column blocks) ----
    k_linear2_mfma<<<256, 512, 0, stream>>>(
        h1, Bhi1, Blo1, bl1, br1, scale0, shift0, xl, xr);
    k_attn<false, NPW><<<attn_blocks, 256, 0, stream>>>(
        xl, xr, se, ea, We1, att1, offs, bias1, h2);
    k_bn_stats<64><<<1024, 256, 0, stream>>>(h2, bns1, bnq1);

    // ---- fused BN-finalize + BN + pool + MLP (graph bounds inline) ----
    k_pool_mlp<<<NG, 256, 0, stream>>>(h2, bns1, bnq1, g1, beta1, bat,
                                       Wm1, bm1, Wm2, bm2, Wm3, bm3, out);
}

// Round 12
// 664.123 us; speedup vs baseline: 1.0376x; 1.0062x over previous
//
#include <hip/hip_runtime.h>
#include <math.h>

constexpr int NN = 50000;
constexpr int NE = 600000;
constexpr int NG = 256;
constexpr int SB = (NN + 255) / 256;  // scan blocks = 196
constexpr float kBnEps = 1e-5f;
constexpr float kSlope = 0.2f;

typedef _Float16 f16x8 __attribute__((ext_vector_type(8)));
typedef float f32x16 __attribute__((ext_vector_type(16)));

__device__ __forceinline__ float rdlane(float v, int l) {
    return __builtin_bit_cast(float, __builtin_amdgcn_readlane(__builtin_bit_cast(int, v), l));
}

// DPP-based add: v += v[permuted lane] — VALU only, no LDS pipe.
template <int CTRL>
__device__ __forceinline__ float dppadd(float v) {
    int t = __builtin_amdgcn_mov_dpp(__builtin_bit_cast(int, v), CTRL, 0xF, 0xF, true);
    return v + __builtin_bit_cast(float, t);
}
// sum over each 16-lane group (all 16 lanes end with the group sum)
__device__ __forceinline__ float sum16(float v) {
    v = dppadd<0xB1>(v);    // quad_perm [1,0,3,2]
    v = dppadd<0x4E>(v);    // quad_perm [2,3,0,1]
    v = dppadd<0x141>(v);   // row_half_mirror
    v = dppadd<0x140>(v);   // row_mirror
    return v;
}

__device__ __forceinline__ float4 fma4(float a, float4 b, float4 c) {
    c.x = fmaf(a, b.x, c.x); c.y = fmaf(a, b.y, c.y);
    c.z = fmaf(a, b.z, c.z); c.w = fmaf(a, b.w, c.w);
    return c;
}

// ---------------- counting sort of edges by dst ----------------
__global__ __launch_bounds__(256) void k_hist(const int* __restrict__ dst, int* __restrict__ cnt)
{
    int e = blockIdx.x * 256 + threadIdx.x;
    if (e < NE) atomicAdd(&cnt[dst[e]], 1);
}

// per-block inclusive scan (unchanged)
__global__ __launch_bounds__(256) void k_scanA(const int* __restrict__ cnt,
                                               int* __restrict__ offs, int* __restrict__ bsum)
{
    __shared__ int s[256];
    int tid = threadIdx.x;
    int i = blockIdx.x * 256 + tid;
    int v = (i < NN) ? cnt[i] : 0;
    s[tid] = v;
    __syncthreads();
    #pragma unroll
    for (int d = 1; d < 256; d <<= 1) {
        int u = (tid >= d) ? s[tid - d] : 0;
        __syncthreads();
        s[tid] += u;
        __syncthreads();
    }
    if (i < NN) offs[i] = s[tid];           // block-local inclusive
    if (tid == 255) bsum[blockIdx.x] = s[255];
}

// r6: scanB folded in — each block reduces raw bsum[0..blockIdx) inline (196 ints).
__global__ __launch_bounds__(256) void k_scanC(const int* __restrict__ cnt,
                                               const int* __restrict__ bsum,
                                               int* __restrict__ offs, int* __restrict__ cur)
{
    __shared__ int sred[256];
    int t = threadIdx.x;
    int b = blockIdx.x;
    int v = (t < SB && t < b) ? bsum[t] : 0;
    sred[t] = v;
    __syncthreads();
    #pragma unroll
    for (int d = 128; d > 0; d >>= 1) {
        if (t < d) sred[t] += sred[t + d];
        __syncthreads();
    }
    int pre = sred[0];                      // exclusive prefix over block sums
    int i = b * 256 + t;
    if (i > NN) return;
    if (i == NN) { offs[NN] = NE; return; }
    int w = offs[i] - cnt[i] + pre;         // global exclusive
    offs[i] = w;
    cur[i] = w;
}

// r6: light scatter — ONE random 8B write per edge. se is the only edge-order
// array; attn reads edge_attr directly from ea via se[].y (r7).
__global__ __launch_bounds__(256) void k_scatter_light(const int* __restrict__ dst,
                                                       const int* __restrict__ src,
                                                       int* __restrict__ cur,
                                                       int2* __restrict__ se)
{
    int e = blockIdx.x * 256 + threadIdx.x;
    if (e < NE) {
        int p = atomicAdd(&cur[dst[e]], 1);
        se[p] = make_int2(src[e], e);
    }
}

// ---------------- W prep for MFMA dual linear (both layers, one dispatch) ----------
// Packed octet index: (kt*512 + col)*2 + g holds B[k = kt*16 + g*8 + i][col],
// col 0..255 -> WL, 256..511 -> WR.
__device__ __forceinline__ void prep_w_body(int T, const float* __restrict__ WL,
                                            const float* __restrict__ WR,
                                            _Float16* __restrict__ bhi,
                                            _Float16* __restrict__ blo)
{
    int g   = T & 1;
    int col = (T >> 1) & 511;
    int kt  = T >> 10;
    const float* W = (col < 256) ? WL : WR;
    int c = col & 255;
    f16x8 h8, l8;
    #pragma unroll
    for (int i = 0; i < 8; ++i) {
        float v = W[(size_t)(kt * 16 + g * 8 + i) * 256 + c];
        _Float16 hv = (_Float16)v;
        h8[i] = hv;
        l8[i] = (_Float16)(v - (float)hv);
    }
    *(f16x8*)(bhi + (size_t)T * 8) = h8;
    *(f16x8*)(blo + (size_t)T * 8) = l8;
}

// grid = 80 blocks: 0..15 -> layer0 (K=64), 16..79 -> layer1 (K=256)
__global__ __launch_bounds__(256) void k_prep_all(
    const float* __restrict__ Wl0, const float* __restrict__ Wr0,
    _Float16* __restrict__ bhi0, _Float16* __restrict__ blo0,
    const float* __restrict__ Wl1, const float* __restrict__ Wr1,
    _Float16* __restrict__ bhi1, _Float16* __restrict__ blo1)
{
    if (blockIdx.x < 16) {
        int T = blockIdx.x * 256 + threadIdx.x;
        prep_w_body(T, Wl0, Wr0, bhi0, blo0);
    } else {
        int T = (blockIdx.x - 16) * 256 + threadIdx.x;
        prep_w_body(T, Wl1, Wr1, bhi1, blo1);
    }
}

// ---------------- fused layer-0 MFMA (FROZEN r8 shape: BM=64, 512 thr) ----------
__global__ __launch_bounds__(512) void k_lin0_mfma(
    const float* __restrict__ x, const float* __restrict__ Win,
    const float* __restrict__ bin,
    const _Float16* __restrict__ Bhi, const _Float16* __restrict__ Blo,
    const float* __restrict__ bl, const float* __restrict__ br,
    float* __restrict__ outl, float* __restrict__ outr)
{
    __shared__ float h0s[64][68];        // +4 pad: rotates bank start per row
    __shared__ f16x8 Apack[2][4][128];   // [hi/lo][kt][slot] 16 KB
    int tid = threadIdx.x;
    int lane = tid & 63, wave = tid >> 6;
    int row0 = blockIdx.x * 64;

    // ---- phase 1: h0 for 8 rows/wave (8 waves = 64 rows), lane = channel ----
    {
        int rbase = row0 + wave * 8;
        float xreg[8];
        #pragma unroll
        for (int j = 0; j < 8; ++j) {
            int row = rbase + j; if (row >= NN) row = NN - 1;
            xreg[j] = x[(size_t)row * 64 + lane];
        }
        float b0 = bin[lane];
        float h0r[8];
        #pragma unroll
        for (int j = 0; j < 8; ++j) h0r[j] = b0;
        for (int k = 0; k < 64; ++k) {
            float w = Win[k * 64 + lane];
            #pragma unroll
            for (int j = 0; j < 8; ++j) h0r[j] = fmaf(rdlane(xreg[j], k), w, h0r[j]);
        }
        #pragma unroll
        for (int j = 0; j < 8; ++j)
            h0s[wave * 8 + j][lane] = fmaxf(h0r[j], 0.f);
    }
    __syncthreads();

    // ---- phase 2: each thread builds one f16 hi/lo fragment (row, 8 k) ----
    {
        int row = tid >> 3;               // 0..63
        int o = (tid & 7) * 8;            // k offset 0..56
        f16x8 hi8, lo8;
        #pragma unroll
        for (int i = 0; i < 8; ++i) {
            float v = h0s[row][o + i];
            _Float16 hv = (_Float16)v;
            hi8[i] = hv;
            lo8[i] = (_Float16)(v - (float)hv);
        }
        int kt = o >> 4, g2 = (o >> 3) & 1;
        int slot = (g2 * 64 + row) ^ kt;  // bijective within 128
        Apack[0][kt][slot] = hi8;
        Apack[1][kt][slot] = lo8;
    }
    __syncthreads();

    // ---- phase 3: MFMA over K=64 ----
    int g = lane >> 5;
    int rowtile = wave >> 2;              // 0 or 1
    int colbase = (wave & 3) * 128 + (lane & 31);
    int aslot = g * 64 + rowtile * 32 + (lane & 31);
    f32x16 acc[4];
    #pragma unroll
    for (int nt = 0; nt < 4; ++nt)
        #pragma unroll
        for (int r = 0; r < 16; ++r) acc[nt][r] = 0.f;

    const f16x8* bh = (const f16x8*)Bhi;
    const f16x8* bo = (const f16x8*)Blo;
    size_t fbase = (size_t)colbase * 2 + g;

    #pragma unroll 1
    for (int kt = 0; kt < 4; ++kt) {
        f16x8 ahi = Apack[0][kt][aslot ^ kt];
        f16x8 alo = Apack[1][kt][aslot ^ kt];
        f16x8 wh[4], wl[4];
        #pragma unroll
        for (int nt = 0; nt < 4; ++nt) {
            size_t fi = fbase + (size_t)kt * 1024 + nt * 64;
            wh[nt] = bh[fi];
            wl[nt] = bo[fi];
        }
        #pragma unroll
        for (int nt = 0; nt < 4; ++nt)
            acc[nt] = __builtin_amdgcn_mfma_f32_32x32x16_f16(ahi, wh[nt], acc[nt], 0, 0, 0);
        #pragma unroll
        for (int nt = 0; nt < 4; ++nt)
            acc[nt] = __builtin_amdgcn_mfma_f32_32x32x16_f16(alo, wh[nt], acc[nt], 0, 0, 0);
        #pragma unroll
        for (int nt = 0; nt < 4; ++nt)
            acc[nt] = __builtin_amdgcn_mfma_f32_32x32x16_f16(ahi, wl[nt], acc[nt], 0, 0, 0);
    }

    // ---- epilogue: bias add, scatter to xl / xr ----
    #pragma unroll
    for (int nt = 0; nt < 4; ++nt) {
        int col = colbase + nt * 32;          // 0..511
        bool isR = col >= 256;
        int c = isR ? col - 256 : col;
        float bv = isR ? br[c] : bl[c];
        float* outp = isR ? outr : outl;
        #pragma unroll
        for (int r = 0; r < 16; ++r) {
            int rowoff = (r & 3) + 8 * (r >> 2) + 4 * g;
            int grow = row0 + rowtile * 32 + rowoff;
            if (grow < NN)
                outp[(size_t)grow * 256 + c] = acc[nt][r] + bv;
        }
    }
}

// ---------------- MFMA dual linear K=256, v5 (FROZEN r11 shape) ----------------
// r9 (WIN -29): register-resident B panels, zero vmem in K-loop.
// r10 dbuf/2-phase REGRESSED (+12); reverted. r11 (WIN -9): 2 column-halves x
// 512-thr blocks — A re-read x2 instead of x4.
__global__ __launch_bounds__(512) void k_linear2_mfma(
    const float* __restrict__ h, const _Float16* __restrict__ Bhi,
    const _Float16* __restrict__ Blo, const float* __restrict__ bl,
    const float* __restrict__ br, const float* __restrict__ scale,
    const float* __restrict__ shift, float* __restrict__ outl,
    float* __restrict__ outr)
{
    __shared__ f16x8 Apack[2][16][64];   // [hi/lo][kt][slot] 32 KB
    int tid = threadIdx.x;
    int lane = tid & 63, wave = tid >> 6;      // 8 waves = 8 colgroups
    int q = blockIdx.x & 1;                    // column half
    int mslot = blockIdx.x >> 1;               // 0..127
    int g = lane >> 5;
    int colbase = q * 256 + wave * 32 + (lane & 31);   // 0..511
    size_t fbase = (size_t)colbase * 2 + g;

    // ---- B resident in registers: 16 kt x (hi+lo) = 128 VGPR ----
    const f16x8* bh = (const f16x8*)Bhi;
    const f16x8* bo = (const f16x8*)Blo;
    f16x8 BH[16], BL[16];
    #pragma unroll
    for (int kt = 0; kt < 16; ++kt) {
        BH[kt] = bh[fbase + (size_t)kt * 1024];
        BL[kt] = bo[fbase + (size_t)kt * 1024];
    }

    bool isR = colbase >= 256;
    int c = isR ? colbase - 256 : colbase;
    float bv = isR ? br[c] : bl[c];
    float* outp = isR ? outr : outl;

    constexpr int NT = (NN + 31) / 32;   // 1563 M-tiles
    for (int t = mslot; t < NT; t += 128) {
        int row0 = t * 32;
        // ---- stage A: 32 rows x 256 k, BN+relu, split (r1 layout; 512 thr:
        //      each thread covers 16 k of one row) ----
        {
            int row  = tid >> 4;              // 0..31
            int koff = (tid & 15) * 16;       // 0..240
            int grow = row0 + row; if (grow >= NN) grow = NN - 1;
            const float* hp = h + (size_t)grow * 256 + koff;
            #pragma unroll
            for (int j2 = 0; j2 < 2; ++j2) {
                int o = koff + j2 * 8;
                float4 a  = *(const float4*)(hp + j2 * 8);
                float4 b  = *(const float4*)(hp + j2 * 8 + 4);
                float4 s0 = *(const float4*)(scale + o);
                float4 s1 = *(const float4*)(scale + o + 4);
                float4 f0 = *(const float4*)(shift + o);
                float4 f1 = *(const float4*)(shift + o + 4);
                float va[8] = {
                    fmaxf(fmaf(a.x, s0.x, f0.x), 0.f), fmaxf(fmaf(a.y, s0.y, f0.y), 0.f),
                    fmaxf(fmaf(a.z, s0.z, f0.z), 0.f), fmaxf(fmaf(a.w, s0.w, f0.w), 0.f),
                    fmaxf(fmaf(b.x, s1.x, f1.x), 0.f), fmaxf(fmaf(b.y, s1.y, f1.y), 0.f),
                    fmaxf(fmaf(b.z, s1.z, f1.z), 0.f), fmaxf(fmaf(b.w, s1.w, f1.w), 0.f)};
                f16x8 hi8, lo8;
                #pragma unroll
                for (int i = 0; i < 8; ++i) {
                    _Float16 hv = (_Float16)va[i];
                    hi8[i] = hv;
                    lo8[i] = (_Float16)(va[i] - (float)hv);
                }
                int kt = o >> 4, g2 = (o >> 3) & 1;
                int slot = (g2 * 32 + row) ^ (kt & 7);
                Apack[0][kt][slot] = hi8;
                Apack[1][kt][slot] = lo8;
            }
        }
        __syncthreads();

        f32x16 acc;
        #pragma unroll
        for (int r = 0; r < 16; ++r) acc[r] = 0.f;

        #pragma unroll
        for (int kt = 0; kt < 16; ++kt) {
            f16x8 ahi = Apack[0][kt][lane ^ (kt & 7)];
            f16x8 alo = Apack[1][kt][lane ^ (kt & 7)];
            acc = __builtin_amdgcn_mfma_f32_32x32x16_f16(ahi, BH[kt], acc, 0, 0, 0);
            acc = __builtin_amdgcn_mfma_f32_32x32x16_f16(alo, BH[kt], acc, 0, 0, 0);
            acc = __builtin_amdgcn_mfma_f32_32x32x16_f16(ahi, BL[kt], acc, 0, 0, 0);
        }
        __syncthreads();   // all waves done reading Apack before next stage

        #pragma unroll
        for (int r = 0; r < 16; ++r) {
            int rowoff = (r & 3) + 8 * (r >> 2) + 4 * g;
            int grow = row0 + rowoff;
            if (grow < NN)
                outp[(size_t)grow * 256 + c] = acc[r] + bv;
        }
    }
}

// ---------------- fused attention (r3 arithmetic core, FROZEN; r7 memory side) ----
// r12: NPW 2 -> 1 (launch-level only; body byte-identical). Halves per-wave
// serial work, doubles wave count -> better degree-variance load balance and
// more independent waves to hide the ~30% memory-stall fraction.
template <bool CONCAT, int NPW>
__global__ __launch_bounds__(256) void k_attn(
    const float* __restrict__ xl, const float* __restrict__ xr,
    const int2* __restrict__ se, const float* __restrict__ ea,
    const float* __restrict__ We, const float* __restrict__ att,
    const int* __restrict__ offs, const float* __restrict__ bias,
    float* __restrict__ out)
{
    int tid = threadIdx.x;
    int lane = tid & 63, wave = tid >> 6;
    float4 wr[16];
    #pragma unroll
    for (int k = 0; k < 16; ++k) wr[k] = ((const float4*)(We + k * 256))[lane];
    float4 ar = ((const float4*)att)[lane];

    int g16 = lane >> 4;
    int k16 = lane & 15;
    int nodebase = (blockIdx.x * 4 + wave) * NPW;
    if (nodebase >= NN) return;

    for (int nn = 0; nn < NPW; ++nn) {
        int n = nodebase + nn;
        if (n >= NN) break;
        int beg = offs[n], end = offs[n + 1];
        float4 xr4 = ((const float4*)(xr + (size_t)n * 256))[lane];

        float m = -INFINITY, ssum = 0.f;
        float4 acc = make_float4(0.f, 0.f, 0.f, 0.f);

        float nea = 0.f;
        float4 nx0, nx1, nx2, nx3;

        auto loadbatch = [&](int i) {
            int idx = i + g16;
            if (idx > end - 1) idx = end - 1;
            int2 sv2 = se[idx];
            nea = ea[(size_t)sv2.y * 16 + k16];
            int sv = sv2.x;
            int s0 = __builtin_amdgcn_readlane(sv, 0);
            int s1 = __builtin_amdgcn_readlane(sv, 16);
            int s2 = __builtin_amdgcn_readlane(sv, 32);
            int s3 = __builtin_amdgcn_readlane(sv, 48);
            nx0 = ((const float4*)(xl + (size_t)s0 * 256))[lane];
            nx1 = ((const float4*)(xl + (size_t)s1 * 256))[lane];
            nx2 = ((const float4*)(xl + (size_t)s2 * 256))[lane];
            nx3 = ((const float4*)(xl + (size_t)s3 * 256))[lane];
        };

        if (beg < end) loadbatch(beg);

        for (int i = beg; i < end; i += 4) {
            float cea = nea;
            float4 x0 = nx0, x1 = nx1, x2 = nx2, x3 = nx3;
            if (i + 4 < end) loadbatch(i + 4);

            float p[4];
            #pragma unroll
            for (int g = 0; g < 4; ++g) {
                float4 xg = (g == 0) ? x0 : (g == 1) ? x1 : (g == 2) ? x2 : x3;
                float4 em = xr4;  // xr folded into accumulator init
                #pragma unroll
                for (int k = 0; k < 16; ++k) {
                    float a = rdlane(cea, g * 16 + k);
                    em.x = fmaf(a, wr[k].x, em.x);
                    em.y = fmaf(a, wr[k].y, em.y);
                    em.z = fmaf(a, wr[k].z, em.z);
                    em.w = fmaf(a, wr[k].w, em.w);
                }
                float z0 = xg.x + em.x;
                float z1 = xg.y + em.y;
                float z2 = xg.z + em.z;
                float z3 = xg.w + em.w;
                z0 = (z0 > 0.f) ? z0 : kSlope * z0;
                z1 = (z1 > 0.f) ? z1 : kSlope * z1;
                z2 = (z2 > 0.f) ? z2 : kSlope * z2;
                z3 = (z3 > 0.f) ? z3 : kSlope * z3;
                float pv = fmaf(z0, ar.x, fmaf(z1, ar.y, fmaf(z2, ar.z, z3 * ar.w)));
                pv = sum16(pv);  // per-head logit (16-lane group), VALU-only DPP
                p[g] = (i + g < end) ? pv : -INFINITY;
            }
            float pm = fmaxf(fmaxf(p[0], p[1]), fmaxf(p[2], p[3]));
            float mn = fmaxf(m, pm);
            float sc = __expf(m - mn);
            float w0 = __expf(p[0] - mn);
            float w1 = __expf(p[1] - mn);
            float w2 = __expf(p[2] - mn);
            float w3 = __expf(p[3] - mn);
            ssum = fmaf(ssum, sc, (w0 + w1) + (w2 + w3));
            acc.x = fmaf(acc.x, sc, fmaf(w0, x0.x, fmaf(w1, x1.x, fmaf(w2, x2.x, w3 * x3.x))));
            acc.y = fmaf(acc.y, sc, fmaf(w0, x0.y, fmaf(w1, x1.y, fmaf(w2, x2.y, w3 * x3.y))));
            acc.z = fmaf(acc.z, sc, fmaf(w0, x0.z, fmaf(w1, x1.z, fmaf(w2, x2.z, w3 * x3.z))));
            acc.w = fmaf(acc.w, sc, fmaf(w0, x0.w, fmaf(w1, x1.w, fmaf(w2, x2.w, w3 * x3.w))));
            m = mn;
        }

        float inv = 1.f / (ssum + 1e-16f);
        if (CONCAT) {
            float4 b4 = ((const float4*)bias)[lane];
            float4 o;
            o.x = fmaf(acc.x, inv, b4.x);
            o.y = fmaf(acc.y, inv, b4.y);
            o.z = fmaf(acc.z, inv, b4.z);
            o.w = fmaf(acc.w, inv, b4.w);
            ((float4*)(out + (size_t)n * 256))[lane] = o;
        } else {
            float v0 = acc.x * inv, v1 = acc.y * inv, v2 = acc.z * inv, v3 = acc.w * inv;
            v0 += __shfl_xor(v0, 16, 64); v0 += __shfl_xor(v0, 32, 64);
            v1 += __shfl_xor(v1, 16, 64); v1 += __shfl_xor(v1, 32, 64);
            v2 += __shfl_xor(v2, 16, 64); v2 += __shfl_xor(v2, 32, 64);
            v3 += __shfl_xor(v3, 16, 64); v3 += __shfl_xor(v3, 32, 64);
            if (lane < 16) {
                float4 b4 = ((const float4*)bias)[lane];
                float4 o;
                o.x = fmaf(0.25f, v0, b4.x);
                o.y = fmaf(0.25f, v1, b4.y);
                o.z = fmaf(0.25f, v2, b4.z);
                o.w = fmaf(0.25f, v3, b4.w);
                ((float4*)(out + (size_t)n * 64))[lane] = o;
            }
        }
    }
}

// ---------------- batchnorm stats (sum, sumsq per channel) ----------------
template <int CH>
__global__ __launch_bounds__(256) void k_bn_stats(const float* __restrict__ h,
                                                  float* __restrict__ sum,
                                                  float* __restrict__ sumsq)
{
    constexpr int RP = 256 / CH;
    int tid = threadIdx.x;
    int c = tid % CH;
    int rsub = tid / CH;
    float s = 0.f, q = 0.f;
    #pragma unroll 4
    for (int n = blockIdx.x * RP + rsub; n < NN; n += gridDim.x * RP) {
        float v = h[(size_t)n * CH + c];
        s += v; q = fmaf(v, v, q);
    }
    __shared__ float ls[256], lq[256];
    ls[tid] = s; lq[tid] = q;
    __syncthreads();
    if (tid < CH) {
        #pragma unroll
        for (int r = 1; r < RP; ++r) { s += ls[tid + r * CH]; q += lq[tid + r * CH]; }
        atomicAdd(&sum[tid], s);
        atomicAdd(&sumsq[tid], q);
    }
}

__global__ void k_bn_finalize(const float* __restrict__ sum, const float* __restrict__ sumsq,
                              const float* __restrict__ g, const float* __restrict__ beta,
                              float* __restrict__ scale, float* __restrict__ shift, int CH)
{
    int c = threadIdx.x;
    if (c >= CH) return;
    float inv_n = 1.f / (float)NN;
    float mu = sum[c] * inv_n;
    float var = sumsq[c] * inv_n - mu * mu;
    float sc = g[c] / sqrtf(var + kBnEps);
    scale[c] = sc;
    shift[c] = fmaf(-mu, sc, beta[c]);
}

// ---------------- fused BN-finalize + BN + mean-pool + MLP head ----------------
__global__ __launch_bounds__(256) void k_pool_mlp(
    const float* __restrict__ h2, const float* __restrict__ bns,
    const float* __restrict__ bnq, const float* __restrict__ gam,
    const float* __restrict__ beta, const int* __restrict__ batch,
    const float* __restrict__ Wm1, const float* __restrict__ bm1,
    const float* __restrict__ Wm2, const float* __restrict__ bm2,
    const float* __restrict__ Wm3, const float* __restrict__ bm3,
    float* __restrict__ out)
{
    int g = blockIdx.x, tid = threadIdx.x;
    int lane = tid & 63, wave = tid >> 6;
    __shared__ int sb[2];
    if (tid < 2) {
        int target = g + tid;
        int lo = 0, hi = NN;
        while (lo < hi) {
            int mid = (lo + hi) >> 1;
            if (batch[mid] < target) lo = mid + 1; else hi = mid;
        }
        sb[tid] = lo;
    }
    __syncthreads();
    int s = sb[0], e = sb[1];
    float inv_n = 1.f / (float)NN;
    float mu = bns[lane] * inv_n;
    float var = bnq[lane] * inv_n - mu * mu;
    float sc = gam[lane] / sqrtf(var + kBnEps);
    float sh = fmaf(-mu, sc, beta[lane]);
    float acc = 0.f;
    #pragma unroll 4
    for (int n = s + wave; n < e; n += 4)
        acc += fmaf(h2[(size_t)n * 64 + lane], sc, sh);
    __shared__ float red[4][64];
    red[wave][lane] = acc;
    __syncthreads();
    __shared__ float p[64], z1[32], z2[16];
    if (tid < 64) {
        float cnt = (float)(e - s);
        float a = red[0][tid] + red[1][tid] + red[2][tid] + red[3][tid];
        p[tid] = a / fmaxf(cnt, 1.f);
    }
    __syncthreads();
    if (tid < 32) {
        float a = bm1[tid];
        #pragma unroll
        for (int k = 0; k < 64; ++k) a = fmaf(p[k], Wm1[k * 32 + tid], a);
        z1[tid] = fmaxf(a, 0.f);
    }
    __syncthreads();
    if (tid < 16) {
        float a = bm2[tid];
        #pragma unroll
        for (int k = 0; k < 32; ++k) a = fmaf(z1[k], Wm2[k * 16 + tid], a);
        z2[tid] = fmaxf(a, 0.f);
    }
    __syncthreads();
    if (tid == 0) {
        float a = bm3[0];
        #pragma unroll
        for (int k = 0; k < 16; ++k) a = fmaf(z2[k], Wm3[k], a);
        out[g] = a;
    }
}

// ---------------- host launcher ----------------
extern "C" void kernel_launch(void* const* d_in, const int* in_sizes, int n_in,
                              void* d_out, int out_size, void* d_ws, size_t ws_size,
                              hipStream_t stream)
{
    const float* x     = (const float*)d_in[0];
    const float* ea    = (const float*)d_in[1];
    const int*   ei    = (const int*)d_in[2];
    const int*   bat   = (const int*)d_in[3];
    const float* W_in  = (const float*)d_in[4];
    const float* b_in  = (const float*)d_in[5];
    const float* Wl0   = (const float*)d_in[6];
    const float* bl0   = (const float*)d_in[7];
    const float* Wr0   = (const float*)d_in[8];
    const float* br0   = (const float*)d_in[9];
    const float* We0   = (const float*)d_in[10];
    const float* att0  = (const float*)d_in[11];
    const float* bias0 = (const float*)d_in[12];
    const float* g0    = (const float*)d_in[13];
    const float* beta0 = (const float*)d_in[14];
    const float* Wl1   = (const float*)d_in[15];
    const float* bl1   = (const float*)d_in[16];
    const float* Wr1   = (const float*)d_in[17];
    const float* br1   = (const float*)d_in[18];
    const float* We1   = (const float*)d_in[19];
    const float* att1  = (const float*)d_in[20];
    const float* bias1 = (const float*)d_in[21];
    const float* g1    = (const float*)d_in[22];
    const float* beta1 = (const float*)d_in[23];
    const float* Wm1   = (const float*)d_in[24];
    const float* bm1   = (const float*)d_in[25];
    const float* Wm2   = (const float*)d_in[26];
    const float* bm2   = (const float*)d_in[27];
    const float* Wm3   = (const float*)d_in[28];
    const float* bm3   = (const float*)d_in[29];
    const int* src = ei;
    const int* dst = ei + NE;
    float* out = (float*)d_out;

    char* p = (char*)d_ws;
    auto take = [&](size_t nbytes) -> char* {
        char* q = p;
        p += (nbytes + 255) & ~(size_t)255;
        return q;
    };
    // ---- zero zone (one memset) ----
    char* z0 = p;
    int*   hist   = (int*)take((size_t)NN * 4);
    float* bns0   = (float*)take(256 * 4);
    float* bnq0   = (float*)take(256 * 4);
    float* bns1   = (float*)take(64 * 4);
    float* bnq1   = (float*)take(64 * 4);
    size_t zbytes = (size_t)(p - z0);
    // ---- rest of workspace ----
    int*   offs   = (int*)take((size_t)(NN + 1) * 4);
    int*   curs   = (int*)take((size_t)NN * 4);
    int*   bsum   = (int*)take((size_t)SB * 4);
    int2*  se     = (int2*)take((size_t)NE * 8);
    float* h2     = (float*)take((size_t)NN * 64 * 4);
    float* xl     = (float*)take((size_t)NN * 256 * 4);
    float* xr     = (float*)take((size_t)NN * 256 * 4);
    float* h1     = (float*)take((size_t)NN * 256 * 4);
    float* scale0 = (float*)take(256 * 4);
    float* shift0 = (float*)take(256 * 4);
    _Float16* Bhi1 = (_Float16*)take((size_t)256 * 512 * 2);
    _Float16* Blo1 = (_Float16*)take((size_t)256 * 512 * 2);
    _Float16* Bhi0 = (_Float16*)take((size_t)64 * 512 * 2);
    _Float16* Blo0 = (_Float16*)take((size_t)64 * 512 * 2);

    hipMemsetAsync(z0, 0, zbytes, stream);

    k_hist<<<(NE + 255) / 256, 256, 0, stream>>>(dst, hist);
    k_prep_all<<<80, 256, 0, stream>>>(Wl0, Wr0, Bhi0, Blo0, Wl1, Wr1, Bhi1, Blo1);
    k_scanA<<<SB, 256, 0, stream>>>(hist, offs, bsum);
    k_scanC<<<SB, 256, 0, stream>>>(hist, bsum, offs, curs);
    k_scatter_light<<<(NE + 255) / 256, 256, 0, stream>>>(dst, src, curs, se);

    constexpr int NPW = 1;
    int attn_blocks = (NN + 4 * NPW - 1) / (4 * NPW);
    int lin0_blocks = (NN + 63) / 64;

    // ---- GATv2 layer 0 (input proj fused into MFMA dual linear) ----
    k_lin0_mfma<<<lin0_blocks, 512, 0, stream>>>(
        x, W_in, b_in, Bhi0, Blo0, bl0, br0, xl, xr);
    k_attn<true, NPW><<<attn_blocks, 256, 0, stream>>>(
        xl, xr, se, ea, We0, att0, offs, bias0, h1);
    k_bn_stats<256><<<1024, 256, 0, stream>>>(h1, bns0, bnq0);
    k_bn_finalize<<<1, 256, 0, stream>>>(bns0, bnq0, g0, beta0, scale0, shift0, 256);

    // ---- GATv2 layer 1: MFMA dual linear v5 (reg-B, half-column blocks) ----
    k_linear2_mfma<<<256, 512, 0, stream>>>(
        h1, Bhi1, Blo1, bl1, br1, scale0, shift0, xl, xr);
    k_attn<false, NPW><<<attn_blocks, 256, 0, stream>>>(
        xl, xr, se, ea, We1, att1, offs, bias1, h2);
    k_bn_stats<64><<<1024, 256, 0, stream>>>(h2, bns1, bnq1);

    // ---- fused BN-finalize + BN + pool + MLP (graph bounds inline) ----
    k_pool_mlp<<<NG, 256, 0, stream>>>(h2, bns1, bnq1, g1, beta1, bat,
                                       Wm1, bm1, Wm2, bm2, Wm3, bm3, out);
}